// Round 8
// baseline (243.510 us; speedup 1.0000x reference)
//
#include <hip/hip_runtime.h>

#define NB 2
#define NP 8192
#define D 64
#define KNN 16

// ---------------- prep: pack (x, y, z, |p|^2) per point ----------------
__global__ void __launch_bounds__(256)
k_prep(const float* __restrict__ xyz, float4* __restrict__ pts4)
{
  const int t = blockIdx.x * 256 + threadIdx.x;   // 0 .. NB*NP-1
  const float x = xyz[t*3+0];
  const float y = xyz[t*3+1];
  const float z = xyz[t*3+2];
  const float sq = __fadd_rn(__fadd_rn(__fmul_rn(x,x), __fmul_rn(y,y)), __fmul_rn(z,z));
  pts4[t] = make_float4(x, y, z, sq);
}

// ---------------- fold delta-MLP: Weff = Wd2@Wd1, beff = Wd2@bd1+bd2 ----------
__global__ void k_fold(const float* __restrict__ Wd1, const float* __restrict__ bd1,
                       const float* __restrict__ Wd2, const float* __restrict__ bd2,
                       float4* __restrict__ weff)
{
  const int c = threadIdx.x;   // 64 threads, 1 block
  float wx = 0.f, wy = 0.f, wz = 0.f, be = bd2[c];
  for (int k = 0; k < 64; ++k) {
    float w = Wd2[c*64 + k];
    wx = fmaf(w, Wd1[k*3+0], wx);
    wy = fmaf(w, Wd1[k*3+1], wy);
    wz = fmaf(w, Wd1[k*3+2], wz);
    be = fmaf(w, bd1[k], be);
  }
  weff[c] = make_float4(wx, wy, wz, be);
}

// ---------------- fold the point-side GEMMs --------------------------------
// block 0: Af = Wg@Wphi@W1, dA = Wg@(Wphi b1 + bphi) + bg
// block 1: Bf = Wg@Wpsi@W1, dB = Wg@(Wpsi b1 + bpsi)
// block 2: Cf = Wal@W1,     dC = Wal b1 + bal
__global__ void __launch_bounds__(256)
k_fold2(const float* __restrict__ Wg,   const float* __restrict__ bg,
        const float* __restrict__ Wphi, const float* __restrict__ bphi,
        const float* __restrict__ Wpsi, const float* __restrict__ bpsi,
        const float* __restrict__ Wal,  const float* __restrict__ bal,
        const float* __restrict__ W1,   const float* __restrict__ b1,
        float* __restrict__ Af, float* __restrict__ dAv,
        float* __restrict__ Bf, float* __restrict__ dBv,
        float* __restrict__ Cf, float* __restrict__ dCv)
{
  __shared__ float sT[64 * 65];   // intermediate T (pad 65, b32 access)
  __shared__ float sTb[64];
  const int m = blockIdx.x;
  const int o = threadIdx.x >> 2;     // out row
  const int q = threadIdx.x & 3;      // 16-col quarter

  const float* O  = (m == 2) ? Wal : Wg;
  const float* M  = (m == 0) ? Wphi : Wpsi;
  const float* bM = (m == 0) ? bphi : bpsi;

  if (m == 2) {
    for (int cc = 0; cc < 16; ++cc) sT[o*65 + q*16 + cc] = Wal[o*64 + q*16 + cc];
    if (q == 0) sTb[o] = bal[o];
  } else {
    float acc[16];
    #pragma unroll
    for (int cc = 0; cc < 16; ++cc) acc[cc] = 0.f;
    for (int k = 0; k < 64; ++k) {
      float w = O[o*64 + k];
      #pragma unroll
      for (int cc = 0; cc < 16; ++cc) acc[cc] = fmaf(w, M[k*64 + q*16 + cc], acc[cc]);
    }
    for (int cc = 0; cc < 16; ++cc) sT[o*65 + q*16 + cc] = acc[cc];
    if (q == 0) {
      float tb = (m == 0) ? bg[o] : 0.f;
      for (int k = 0; k < 64; ++k) tb = fmaf(O[o*64 + k], bM[k], tb);
      sTb[o] = tb;
    }
  }
  __syncthreads();

  // stage 2: R = T @ W1, dR = T @ b1 + Tb
  float acc[16];
  #pragma unroll
  for (int cc = 0; cc < 16; ++cc) acc[cc] = 0.f;
  for (int k = 0; k < 64; ++k) {
    float w = sT[o*65 + k];
    #pragma unroll
    for (int cc = 0; cc < 16; ++cc) acc[cc] = fmaf(w, W1[k*64 + q*16 + cc], acc[cc]);
  }
  float* R  = (m == 0) ? Af  : (m == 1) ? Bf  : Cf;
  float* dR = (m == 0) ? dAv : (m == 1) ? dBv : dCv;
  for (int cc = 0; cc < 16; ++cc) R[o*64 + q*16 + cc] = acc[cc];
  if (q == 0) {
    float db = sTb[o];
    for (int k = 0; k < 64; ++k) db = fmaf(sT[o*65 + k], b1[k], db);
    dR[o] = db;
  }
}

// ---------------- per-point GEMVs: uA = Af x + dA, uB = Bf x + dB, uC = Cf x + dC
__global__ void __launch_bounds__(256, 4)
k_transform2(const float* __restrict__ feat,
             const float* __restrict__ Af, const float* __restrict__ dAv,
             const float* __restrict__ Bf, const float* __restrict__ dBv,
             const float* __restrict__ Cf, const float* __restrict__ dCv,
             float* __restrict__ uA, float* __restrict__ uB, float* __restrict__ uC)
{
  __shared__ float sA[64*68], sB[64*68], sC[64*68];  // pad 68: b128-aligned, bank-spread
  __shared__ float sdA[64], sdB[64], sdC[64];

  const int tid = threadIdx.x;
  for (int e = tid; e < 4096; e += 256) {
    const int r = e >> 6, c = e & 63;
    sA[r*68 + c] = Af[e];
    sB[r*68 + c] = Bf[e];
    sC[r*68 + c] = Cf[e];
  }
  if (tid < 64) { sdA[tid] = dAv[tid]; sdB[tid] = dBv[tid]; sdC[tid] = dCv[tid]; }
  __syncthreads();

  const int q  = tid & 7;                       // out-eighth; rows o = q + 8i
  const int pt = blockIdx.x * 32 + (tid >> 3);
  const size_t row = (size_t)pt * D;

  float x[64];
  {
    const float4* xr = (const float4*)(feat + row);
    #pragma unroll
    for (int cc = 0; cc < 16; ++cc) {
      float4 v = xr[cc];
      x[cc*4+0] = v.x; x[cc*4+1] = v.y; x[cc*4+2] = v.z; x[cc*4+3] = v.w;
    }
  }

#define GEMV8(SM, SD, OUT)                                              \
  {                                                                     \
    float acc[8];                                                       \
    _Pragma("unroll")                                                   \
    for (int i = 0; i < 8; ++i) acc[i] = SD[q + 8*i];                   \
    _Pragma("unroll")                                                   \
    for (int i = 0; i < 8; ++i) {                                       \
      const int o = q + 8*i;                                            \
      const float4* wr = (const float4*)(SM + o*68);                    \
      _Pragma("unroll")                                                 \
      for (int c4 = 0; c4 < 16; ++c4) {                                 \
        float4 w = wr[c4];                                              \
        acc[i] = fmaf(w.x, x[c4*4+0], acc[i]);                          \
        acc[i] = fmaf(w.y, x[c4*4+1], acc[i]);                          \
        acc[i] = fmaf(w.z, x[c4*4+2], acc[i]);                          \
        acc[i] = fmaf(w.w, x[c4*4+3], acc[i]);                          \
      }                                                                 \
    }                                                                   \
    _Pragma("unroll")                                                   \
    for (int i = 0; i < 8; ++i) OUT[row + q + 8*i] = acc[i];            \
  }

  GEMV8(sA, sdA, uA)
  GEMV8(sB, sdB, uB)
  GEMV8(sC, sdC, uC)
#undef GEMV8
}

// ---------------- KNN v5: bitonic init, (ds,idx) split keys, lazy threshold ----
__global__ void __launch_bounds__(256)
k_knn5(const float4* __restrict__ pts4, int* __restrict__ knn_idx)
{
  const int q    = (blockIdx.x * 256 + threadIdx.x) >> 6;  // global query id
  const int lane = threadIdx.x & 63;
  const int b    = q >> 13;
  const float4* pb = pts4 + (size_t)b * NP;

  const float4 qp = pb[q & (NP - 1)];          // uniform per wave
  const float xi = qp.x, yi = qp.y, zi = qp.z, sqi = qp.w;

  float4 a0 = pb[lane], a1 = pb[64 + lane], a2 = pb[128 + lane], a3 = pb[192 + lane];

  // ---- init: batch 0 via full-wave bitonic sort of (ds, idx) ----
  unsigned kds, kidx;
  {
    float dot = __fadd_rn(__fadd_rn(__fmul_rn(xi,a0.x), __fmul_rn(yi,a0.y)), __fmul_rn(zi,a0.z));
    float d2  = __fsub_rn(__fadd_rn(sqi, a0.w), __fmul_rn(2.0f, dot));
    float ds  = __fsqrt_rn(fmaxf(d2, 0.0f));
    kds = __float_as_uint(ds);
    kidx = (unsigned)lane;
  }
  #pragma unroll
  for (int k = 2; k <= 64; k <<= 1) {
    #pragma unroll
    for (int jj = k >> 1; jj >= 1; jj >>= 1) {
      unsigned ods  = __shfl_xor(kds,  jj, 64);
      unsigned oidx = __shfl_xor(kidx, jj, 64);
      const bool up    = (lane & k) == 0;
      const bool lower = (lane & jj) == 0;
      const bool takemin = (lower == up);
      const bool oless = (ods < kds) || ((ods == kds) && (oidx < kidx));
      const bool take = (takemin == oless);
      kds  = take ? ods  : kds;
      kidx = take ? oidx : kidx;
    }
  }
  if (lane >= KNN) { kds = 0x7F7FFFFFu; kidx = 0xFFFFu; }

  float thr_d2;
  {
    float d16 = __uint_as_float((unsigned)__builtin_amdgcn_readlane((int)kds, KNN - 1));
    thr_d2 = __fmul_rn(__fmul_rn(d16, d16), 1.000001f);
  }

#define KPROC(P, CIDX)                                                                   \
  {                                                                                      \
    float dot = __fadd_rn(__fadd_rn(__fmul_rn(xi,(P).x), __fmul_rn(yi,(P).y)),           \
                          __fmul_rn(zi,(P).z));                                          \
    float d2  = __fsub_rn(__fadd_rn(sqi, (P).w), __fmul_rn(2.0f, dot));                  \
    unsigned long long mask = __ballot(d2 <= thr_d2);                                    \
    if (mask) {                                                                          \
      float ds = __fsqrt_rn(fmaxf(d2, 0.0f));                                            \
      unsigned cds = __float_as_uint(ds);                                                \
      unsigned cidx = (unsigned)((CIDX)*64 + lane);                                      \
      bool ins = false;                                                                  \
      do {                                                                               \
        const int src = __ffsll((long long)mask) - 1;                                    \
        mask &= mask - 1;                                                                \
        const unsigned ids  = (unsigned)__builtin_amdgcn_readlane((int)cds,  src);       \
        const unsigned iidx = (unsigned)__builtin_amdgcn_readlane((int)cidx, src);       \
        const bool less = (kds < ids) || ((kds == ids) && (kidx < iidx));                \
        const int pos = __popcll(__ballot((lane < KNN) && less));                        \
        if (pos < KNN) {                                                                 \
          unsigned uds  = __shfl_up(kds,  1, 64);                                        \
          unsigned uidx = __shfl_up(kidx, 1, 64);                                        \
          if (lane < KNN) {                                                              \
            kds  = (lane < pos) ? kds  : (lane == pos ? ids  : uds);                     \
            kidx = (lane < pos) ? kidx : (lane == pos ? iidx : uidx);                    \
          }                                                                              \
          ins = true;                                                                    \
        }                                                                                \
      } while (mask);                                                                    \
      if (ins) {                                                                         \
        float d16 = __uint_as_float((unsigned)__builtin_amdgcn_readlane((int)kds, KNN-1)); \
        thr_d2 = __fmul_rn(__fmul_rn(d16, d16), 1.000001f);                              \
      }                                                                                  \
    }                                                                                    \
  }

  // prefetch batches 4..7, process 1..3
  float4 n0 = pb[256 + lane], n1 = pb[320 + lane], n2 = pb[384 + lane], n3 = pb[448 + lane];
  KPROC(a1, 1) KPROC(a2, 2) KPROC(a3, 3)
  a0 = n0; a1 = n1; a2 = n2; a3 = n3;

  #pragma unroll 1
  for (int g = 1; g < 32; ++g) {
    if (g < 31) {
      const int base = (g + 1) * 256 + lane;
      n0 = pb[base]; n1 = pb[base + 64]; n2 = pb[base + 128]; n3 = pb[base + 192];
    }
    KPROC(a0, g*4+0) KPROC(a1, g*4+1) KPROC(a2, g*4+2) KPROC(a3, g*4+3)
    a0 = n0; a1 = n1; a2 = n2; a3 = n3;
  }
#undef KPROC

  if (lane < KNN) knn_idx[(size_t)q * KNN + lane] = (int)kidx;
}

// ---------------- main kernel v4: gamma-only register state, no spills ----------
// gamma = uA_i - uB_j + Wg@delta ; alpha = uC_j + delta ; delta recomputed on the fly.
// LDS column pack: sComb[c*68 + {0..3}] = weff_c, sComb[c*68 + 4 + o] = Wg[o][c].
__global__ void __launch_bounds__(256, 4)
k_main4(const float* __restrict__ xyz,
        const float* __restrict__ feat,
        const int* __restrict__ knn_idx,
        const float* __restrict__ uA, const float* __restrict__ uB, const float* __restrict__ uC,
        const float4* __restrict__ weff,
        const float* __restrict__ Wg,
        const float* __restrict__ W2g, const float* __restrict__ b2g,
        float* __restrict__ out)
{
  __shared__ float sComb[64 * 68];    // 17 KB: [weff | WgT column] per input channel
  __shared__ float sW2[64 * 68];      // 17 KB: W2 rows, +68 pad, b128-aligned
  __shared__ float sB2[64];

  const int tid = threadIdx.x;
  {
    #pragma unroll
    for (int it = 0; it < 16; ++it) {
      const int e = it*256 + tid;     // Wg/W2 linear element, e = o*64 + c
      const int o = e >> 6, c = e & 63;
      sComb[c*68 + 4 + o] = Wg[e];
      sW2[o*68 + c]       = W2g[e];
    }
    if (tid < 64) {
      sB2[tid] = b2g[tid];
      float4 wf = weff[tid];
      sComb[tid*68 + 0] = wf.x; sComb[tid*68 + 1] = wf.y;
      sComb[tid*68 + 2] = wf.z; sComb[tid*68 + 3] = wf.w;
    }
  }
  __syncthreads();

  const int lane  = tid & 63;
  const int kslot = lane & 15;
  const int point = blockIdx.x * 16 + (tid >> 6) * 4 + (lane >> 4);
  const int b     = point >> 13;
  const int i     = point & (NP - 1);
  const size_t irow = (size_t)point * D;

  const int j = knn_idx[(size_t)blockIdx.x * 256 + tid];
  const size_t jrow = ((size_t)(b * NP + j)) * D;

  const float* xb = xyz + (size_t)b * NP * 3;
  const float dx = xb[i*3+0] - xb[j*3+0];
  const float dy = xb[i*3+1] - xb[j*3+1];
  const float dz = xb[i*3+2] - xb[j*3+2];

  // ---- gamma init: uA_i - uB_j ----
  float gamma[64];
  {
    const float4* ua = (const float4*)(uA + irow);
    const float4* ub = (const float4*)(uB + jrow);
    #pragma unroll
    for (int cc = 0; cc < 16; ++cc) {
      float4 a = ua[cc];
      float4 v = ub[cc];
      gamma[cc*4+0] = a.x - v.x; gamma[cc*4+1] = a.y - v.y;
      gamma[cc*4+2] = a.z - v.z; gamma[cc*4+3] = a.w - v.w;
    }
  }

  // ---- gamma += Wg @ delta, delta computed per input channel (never stored) ----
  #pragma unroll 4
  for (int c = 0; c < 64; ++c) {
    const float4* col = (const float4*)(sComb + c*68);   // wave-uniform
    float4 wf = col[0];
    float t = fmaf(wf.z, dz, fmaf(wf.y, dy, fmaf(wf.x, dx, wf.w)));
    float d = fmaxf(t, 0.f);
    #pragma unroll
    for (int o4 = 0; o4 < 16; ++o4) {
      float4 w = col[1 + o4];
      gamma[o4*4+0] = fmaf(w.x, d, gamma[o4*4+0]);
      gamma[o4*4+1] = fmaf(w.y, d, gamma[o4*4+1]);
      gamma[o4*4+2] = fmaf(w.z, d, gamma[o4*4+2]);
      gamma[o4*4+3] = fmaf(w.w, d, gamma[o4*4+3]);
    }
  }

  // ---- lane-local softmax over 64 channels ----
  float m0 = gamma[0], m1 = gamma[1], m2 = gamma[2], m3 = gamma[3];
  #pragma unroll
  for (int c = 4; c < 64; c += 4) {
    m0 = fmaxf(m0, gamma[c+0]); m1 = fmaxf(m1, gamma[c+1]);
    m2 = fmaxf(m2, gamma[c+2]); m3 = fmaxf(m3, gamma[c+3]);
  }
  const float m = fmaxf(fmaxf(m0, m1), fmaxf(m2, m3));
  float s0 = 0.f, s1 = 0.f, s2 = 0.f, s3 = 0.f;
  #pragma unroll
  for (int c = 0; c < 64; c += 4) {
    gamma[c+0] = __expf(gamma[c+0] - m); s0 += gamma[c+0];
    gamma[c+1] = __expf(gamma[c+1] - m); s1 += gamma[c+1];
    gamma[c+2] = __expf(gamma[c+2] - m); s2 += gamma[c+2];
    gamma[c+3] = __expf(gamma[c+3] - m); s3 += gamma[c+3];
  }
  const float inv = 1.0f / ((s0 + s1) + (s2 + s3));

  // ---- alpha = uC_j + delta (recomputed); acc over K across 16 kslot lanes ----
  {
    const float4* uc = (const float4*)(uC + jrow);
    #pragma unroll
    for (int cc = 0; cc < 16; ++cc) {
      float4 av = uc[cc];
      float avv[4] = {av.x, av.y, av.z, av.w};
      #pragma unroll
      for (int r = 0; r < 4; ++r) {
        const int c = cc*4 + r;
        const float4* col = (const float4*)(sComb + c*68);
        float4 wf = col[0];
        float t = fmaf(wf.z, dz, fmaf(wf.y, dy, fmaf(wf.x, dx, wf.w)));
        float d = fmaxf(t, 0.f);
        float v = gamma[c] * inv * (avv[r] + d);
        v += __shfl_xor(v, 1, 64);
        v += __shfl_xor(v, 2, 64);
        v += __shfl_xor(v, 4, 64);
        v += __shfl_xor(v, 8, 64);
        gamma[c] = v;                   // per-point acc, replicated in 16 lanes
      }
    }
  }

  // ---- epilogue: out = acc @ W2^T + b2 + feat; lane kslot does 4 channels ----
  const int oc = kslot * 4;
  float o0 = sB2[oc+0], o1 = sB2[oc+1], o2 = sB2[oc+2], o3 = sB2[oc+3];
  {
    const float4* r0 = (const float4*)(sW2 + (oc+0)*68);
    const float4* r1 = (const float4*)(sW2 + (oc+1)*68);
    const float4* r2 = (const float4*)(sW2 + (oc+2)*68);
    const float4* r3 = (const float4*)(sW2 + (oc+3)*68);
    #pragma unroll
    for (int c4 = 0; c4 < 16; ++c4) {
      float4 w0 = r0[c4], w1 = r1[c4], w2 = r2[c4], w3 = r3[c4];
      o0 = fmaf(w0.x, gamma[c4*4+0], o0); o0 = fmaf(w0.y, gamma[c4*4+1], o0);
      o0 = fmaf(w0.z, gamma[c4*4+2], o0); o0 = fmaf(w0.w, gamma[c4*4+3], o0);
      o1 = fmaf(w1.x, gamma[c4*4+0], o1); o1 = fmaf(w1.y, gamma[c4*4+1], o1);
      o1 = fmaf(w1.z, gamma[c4*4+2], o1); o1 = fmaf(w1.w, gamma[c4*4+3], o1);
      o2 = fmaf(w2.x, gamma[c4*4+0], o2); o2 = fmaf(w2.y, gamma[c4*4+1], o2);
      o2 = fmaf(w2.z, gamma[c4*4+2], o2); o2 = fmaf(w2.w, gamma[c4*4+3], o2);
      o3 = fmaf(w3.x, gamma[c4*4+0], o3); o3 = fmaf(w3.y, gamma[c4*4+1], o3);
      o3 = fmaf(w3.z, gamma[c4*4+2], o3); o3 = fmaf(w3.w, gamma[c4*4+3], o3);
    }
  }
  float4 fv = *(const float4*)(feat + irow + oc);
  *(float4*)(out + irow + oc) = make_float4(o0 + fv.x, o1 + fv.y, o2 + fv.z, o3 + fv.w);
}

extern "C" void kernel_launch(void* const* d_in, const int* in_sizes, int n_in,
                              void* d_out, int out_size, void* d_ws, size_t ws_size,
                              hipStream_t stream) {
  const float* xyz  = (const float*)d_in[0];
  const float* feat = (const float*)d_in[1];
  // d_in[2] = k (int32) == 16, compile-time constant here
  const float* W1   = (const float*)d_in[3];
  const float* b1   = (const float*)d_in[4];
  const float* Wphi = (const float*)d_in[5];
  const float* bphi = (const float*)d_in[6];
  const float* Wpsi = (const float*)d_in[7];
  const float* bpsi = (const float*)d_in[8];
  const float* Wal  = (const float*)d_in[9];
  const float* bal  = (const float*)d_in[10];
  const float* Wg   = (const float*)d_in[11];
  const float* bg   = (const float*)d_in[12];
  const float* Wd1  = (const float*)d_in[13];
  const float* bd1  = (const float*)d_in[14];
  const float* Wd2  = (const float*)d_in[15];
  const float* bd2  = (const float*)d_in[16];
  const float* W2   = (const float*)d_in[17];
  const float* b2   = (const float*)d_in[18];

  float* out = (float*)d_out;

  // workspace layout (f32 words): uA | uB | uC | knn_idx | pts4 | weff | folds
  const size_t NPT = (size_t)NB * NP;     // 16384
  float* uA = (float*)d_ws;
  float* uB = uA + NPT * D;
  float* uC = uB + NPT * D;
  int* knn_idx = (int*)(uC + NPT * D);
  float4* pts4 = (float4*)(knn_idx + NPT * KNN);
  float4* weff = pts4 + NPT;
  float* Af  = (float*)(weff + 64);
  float* dAv = Af + 4096;
  float* Bf  = dAv + 64;
  float* dBv = Bf + 4096;
  float* Cf  = dBv + 64;
  float* dCv = Cf + 4096;

  // output 0: points_xyz passthrough (f32)
  hipMemcpyAsync(d_out, d_in[0], NPT * 3 * sizeof(float),
                 hipMemcpyDeviceToDevice, stream);

  k_prep<<<NPT / 256, 256, 0, stream>>>(xyz, pts4);
  k_fold<<<1, 64, 0, stream>>>(Wd1, bd1, Wd2, bd2, weff);
  k_fold2<<<3, 256, 0, stream>>>(Wg, bg, Wphi, bphi, Wpsi, bpsi, Wal, bal, W1, b1,
                                 Af, dAv, Bf, dBv, Cf, dCv);
  k_transform2<<<NPT / 32, 256, 0, stream>>>(feat, Af, dAv, Bf, dBv, Cf, dCv, uA, uB, uC);
  k_knn5<<<NPT / 4, 256, 0, stream>>>(pts4, knn_idx);
  k_main4<<<NPT / 16, 256, 0, stream>>>(xyz, feat, knn_idx, uA, uB, uC, weff,
                                        Wg, W2, b2, out + NPT * 3);
}

// Round 9
// 229.549 us; speedup vs baseline: 1.0608x; 1.0608x over previous
//
#include <hip/hip_runtime.h>

#define NB 2
#define NP 8192
#define D 64
#define KNN 16

// ---------------- prep: pack (x, y, z, |p|^2) per point ----------------
__global__ void __launch_bounds__(256)
k_prep(const float* __restrict__ xyz, float4* __restrict__ pts4)
{
  const int t = blockIdx.x * 256 + threadIdx.x;   // 0 .. NB*NP-1
  const float x = xyz[t*3+0];
  const float y = xyz[t*3+1];
  const float z = xyz[t*3+2];
  const float sq = __fadd_rn(__fadd_rn(__fmul_rn(x,x), __fmul_rn(y,y)), __fmul_rn(z,z));
  pts4[t] = make_float4(x, y, z, sq);
}

// ---------------- fold delta-MLP: Weff = Wd2@Wd1, beff = Wd2@bd1+bd2 ----------
__global__ void k_fold(const float* __restrict__ Wd1, const float* __restrict__ bd1,
                       const float* __restrict__ Wd2, const float* __restrict__ bd2,
                       float4* __restrict__ weff)
{
  const int c = threadIdx.x;   // 64 threads, 1 block
  float wx = 0.f, wy = 0.f, wz = 0.f, be = bd2[c];
  for (int k = 0; k < 64; ++k) {
    float w = Wd2[c*64 + k];
    wx = fmaf(w, Wd1[k*3+0], wx);
    wy = fmaf(w, Wd1[k*3+1], wy);
    wz = fmaf(w, Wd1[k*3+2], wz);
    be = fmaf(w, bd1[k], be);
  }
  weff[c] = make_float4(wx, wy, wz, be);
}

// ---------------- pack per-channel records: comb[c*68] = [weff_c(4) | WgT col c(64)]
__global__ void k_fold3(const float4* __restrict__ weff, const float* __restrict__ Wg,
                        float* __restrict__ comb)
{
  const int tid = threadIdx.x;   // 256 threads, 1 block
  #pragma unroll
  for (int it = 0; it < 16; ++it) {
    const int e = it*256 + tid;  // e = o*64 + c
    const int o = e >> 6, c = e & 63;
    comb[c*68 + 4 + o] = Wg[e];
  }
  if (tid < 64) {
    float4 wf = weff[tid];
    comb[tid*68+0] = wf.x; comb[tid*68+1] = wf.y;
    comb[tid*68+2] = wf.z; comb[tid*68+3] = wf.w;
  }
}

// ---------------- fold the point-side GEMMs --------------------------------
// block 0: Af = Wg@Wphi@W1, dA = Wg@(Wphi b1 + bphi) + bg
// block 1: Bf = Wg@Wpsi@W1, dB = Wg@(Wpsi b1 + bpsi)
// block 2: Cf = Wal@W1,     dC = Wal b1 + bal
__global__ void __launch_bounds__(256)
k_fold2(const float* __restrict__ Wg,   const float* __restrict__ bg,
        const float* __restrict__ Wphi, const float* __restrict__ bphi,
        const float* __restrict__ Wpsi, const float* __restrict__ bpsi,
        const float* __restrict__ Wal,  const float* __restrict__ bal,
        const float* __restrict__ W1,   const float* __restrict__ b1,
        float* __restrict__ Af, float* __restrict__ dAv,
        float* __restrict__ Bf, float* __restrict__ dBv,
        float* __restrict__ Cf, float* __restrict__ dCv)
{
  __shared__ float sT[64 * 65];   // intermediate T (pad 65, b32 access)
  __shared__ float sTb[64];
  const int m = blockIdx.x;
  const int o = threadIdx.x >> 2;     // out row
  const int q = threadIdx.x & 3;      // 16-col quarter

  const float* O  = (m == 2) ? Wal : Wg;
  const float* M  = (m == 0) ? Wphi : Wpsi;
  const float* bM = (m == 0) ? bphi : bpsi;

  if (m == 2) {
    for (int cc = 0; cc < 16; ++cc) sT[o*65 + q*16 + cc] = Wal[o*64 + q*16 + cc];
    if (q == 0) sTb[o] = bal[o];
  } else {
    float acc[16];
    #pragma unroll
    for (int cc = 0; cc < 16; ++cc) acc[cc] = 0.f;
    for (int k = 0; k < 64; ++k) {
      float w = O[o*64 + k];
      #pragma unroll
      for (int cc = 0; cc < 16; ++cc) acc[cc] = fmaf(w, M[k*64 + q*16 + cc], acc[cc]);
    }
    for (int cc = 0; cc < 16; ++cc) sT[o*65 + q*16 + cc] = acc[cc];
    if (q == 0) {
      float tb = (m == 0) ? bg[o] : 0.f;
      for (int k = 0; k < 64; ++k) tb = fmaf(O[o*64 + k], bM[k], tb);
      sTb[o] = tb;
    }
  }
  __syncthreads();

  // stage 2: R = T @ W1, dR = T @ b1 + Tb
  float acc[16];
  #pragma unroll
  for (int cc = 0; cc < 16; ++cc) acc[cc] = 0.f;
  for (int k = 0; k < 64; ++k) {
    float w = sT[o*65 + k];
    #pragma unroll
    for (int cc = 0; cc < 16; ++cc) acc[cc] = fmaf(w, W1[k*64 + q*16 + cc], acc[cc]);
  }
  float* R  = (m == 0) ? Af  : (m == 1) ? Bf  : Cf;
  float* dR = (m == 0) ? dAv : (m == 1) ? dBv : dCv;
  for (int cc = 0; cc < 16; ++cc) R[o*64 + q*16 + cc] = acc[cc];
  if (q == 0) {
    float db = sTb[o];
    for (int k = 0; k < 64; ++k) db = fmaf(sT[o*65 + k], b1[k], db);
    dR[o] = db;
  }
}

// ---------------- per-point GEMVs v3: lane = point, scalar weight loads --------
// grid (64, 12): blockIdx.y -> matrix m = y>>2, row block rb = (y&3)*16
__global__ void __launch_bounds__(256, 2)
k_transform3(const float* __restrict__ feat,
             const float* __restrict__ Af, const float* __restrict__ dAv,
             const float* __restrict__ Bf, const float* __restrict__ dBv,
             const float* __restrict__ Cf, const float* __restrict__ dCv,
             float* __restrict__ uA, float* __restrict__ uB, float* __restrict__ uC)
{
  const int tid   = threadIdx.x;
  const int chunk = blockIdx.y;                 // 0..11
  const int m     = chunk >> 2;
  const int rb    = (chunk & 3) << 4;           // row base
  const float* __restrict__ M  = (m == 0) ? Af  : ((m == 1) ? Bf  : Cf);
  const float* __restrict__ dv = (m == 0) ? dAv : ((m == 1) ? dBv : dCv);
  float* __restrict__ O        = (m == 0) ? uA  : ((m == 1) ? uB  : uC);

  const size_t pt = (size_t)blockIdx.x * 256 + tid;
  const float4* xr = (const float4*)(feat + pt * D);
  float x[64];
  #pragma unroll
  for (int c4 = 0; c4 < 16; ++c4) {
    float4 v = xr[c4];
    x[c4*4+0] = v.x; x[c4*4+1] = v.y; x[c4*4+2] = v.z; x[c4*4+3] = v.w;
  }

  float acc[16];
  #pragma unroll
  for (int r = 0; r < 16; ++r) {
    acc[r] = dv[rb + r];                        // uniform -> scalar load
    const float4* wr = (const float4*)(M + (size_t)(rb + r) * D);  // uniform rows
    #pragma unroll
    for (int c4 = 0; c4 < 16; ++c4) {
      float4 w = wr[c4];
      acc[r] = fmaf(w.x, x[c4*4+0], acc[r]);
      acc[r] = fmaf(w.y, x[c4*4+1], acc[r]);
      acc[r] = fmaf(w.z, x[c4*4+2], acc[r]);
      acc[r] = fmaf(w.w, x[c4*4+3], acc[r]);
    }
  }
  float4* op = (float4*)(O + pt * D + rb);
  #pragma unroll
  for (int q = 0; q < 4; ++q)
    op[q] = make_float4(acc[q*4+0], acc[q*4+1], acc[q*4+2], acc[q*4+3]);
}

// ---------------- KNN v5: bitonic init, (ds,idx) split keys, lazy threshold ----
__global__ void __launch_bounds__(256)
k_knn5(const float4* __restrict__ pts4, int* __restrict__ knn_idx)
{
  const int q    = (blockIdx.x * 256 + threadIdx.x) >> 6;  // global query id
  const int lane = threadIdx.x & 63;
  const int b    = q >> 13;
  const float4* pb = pts4 + (size_t)b * NP;

  const float4 qp = pb[q & (NP - 1)];          // uniform per wave
  const float xi = qp.x, yi = qp.y, zi = qp.z, sqi = qp.w;

  float4 a0 = pb[lane], a1 = pb[64 + lane], a2 = pb[128 + lane], a3 = pb[192 + lane];

  // ---- init: batch 0 via full-wave bitonic sort of (ds, idx) ----
  unsigned kds, kidx;
  {
    float dot = __fadd_rn(__fadd_rn(__fmul_rn(xi,a0.x), __fmul_rn(yi,a0.y)), __fmul_rn(zi,a0.z));
    float d2  = __fsub_rn(__fadd_rn(sqi, a0.w), __fmul_rn(2.0f, dot));
    float ds  = __fsqrt_rn(fmaxf(d2, 0.0f));
    kds = __float_as_uint(ds);
    kidx = (unsigned)lane;
  }
  #pragma unroll
  for (int k = 2; k <= 64; k <<= 1) {
    #pragma unroll
    for (int jj = k >> 1; jj >= 1; jj >>= 1) {
      unsigned ods  = __shfl_xor(kds,  jj, 64);
      unsigned oidx = __shfl_xor(kidx, jj, 64);
      const bool up    = (lane & k) == 0;
      const bool lower = (lane & jj) == 0;
      const bool takemin = (lower == up);
      const bool oless = (ods < kds) || ((ods == kds) && (oidx < kidx));
      const bool take = (takemin == oless);
      kds  = take ? ods  : kds;
      kidx = take ? oidx : kidx;
    }
  }
  if (lane >= KNN) { kds = 0x7F7FFFFFu; kidx = 0xFFFFu; }

  float thr_d2;
  {
    float d16 = __uint_as_float((unsigned)__builtin_amdgcn_readlane((int)kds, KNN - 1));
    thr_d2 = __fmul_rn(__fmul_rn(d16, d16), 1.000001f);
  }

#define KPROC(P, CIDX)                                                                   \
  {                                                                                      \
    float dot = __fadd_rn(__fadd_rn(__fmul_rn(xi,(P).x), __fmul_rn(yi,(P).y)),           \
                          __fmul_rn(zi,(P).z));                                          \
    float d2  = __fsub_rn(__fadd_rn(sqi, (P).w), __fmul_rn(2.0f, dot));                  \
    unsigned long long mask = __ballot(d2 <= thr_d2);                                    \
    if (mask) {                                                                          \
      float ds = __fsqrt_rn(fmaxf(d2, 0.0f));                                            \
      unsigned cds = __float_as_uint(ds);                                                \
      unsigned cidx = (unsigned)((CIDX)*64 + lane);                                      \
      bool ins = false;                                                                  \
      do {                                                                               \
        const int src = __ffsll((long long)mask) - 1;                                    \
        mask &= mask - 1;                                                                \
        const unsigned ids  = (unsigned)__builtin_amdgcn_readlane((int)cds,  src);       \
        const unsigned iidx = (unsigned)__builtin_amdgcn_readlane((int)cidx, src);       \
        const bool less = (kds < ids) || ((kds == ids) && (kidx < iidx));                \
        const int pos = __popcll(__ballot((lane < KNN) && less));                        \
        if (pos < KNN) {                                                                 \
          unsigned uds  = __shfl_up(kds,  1, 64);                                        \
          unsigned uidx = __shfl_up(kidx, 1, 64);                                        \
          if (lane < KNN) {                                                              \
            kds  = (lane < pos) ? kds  : (lane == pos ? ids  : uds);                     \
            kidx = (lane < pos) ? kidx : (lane == pos ? iidx : uidx);                    \
          }                                                                              \
          ins = true;                                                                    \
        }                                                                                \
      } while (mask);                                                                    \
      if (ins) {                                                                         \
        float d16 = __uint_as_float((unsigned)__builtin_amdgcn_readlane((int)kds, KNN-1)); \
        thr_d2 = __fmul_rn(__fmul_rn(d16, d16), 1.000001f);                              \
      }                                                                                  \
    }                                                                                    \
  }

  // prefetch batches 4..7, process 1..3
  float4 n0 = pb[256 + lane], n1 = pb[320 + lane], n2 = pb[384 + lane], n3 = pb[448 + lane];
  KPROC(a1, 1) KPROC(a2, 2) KPROC(a3, 3)
  a0 = n0; a1 = n1; a2 = n2; a3 = n3;

  #pragma unroll 1
  for (int g = 1; g < 32; ++g) {
    if (g < 31) {
      const int base = (g + 1) * 256 + lane;
      n0 = pb[base]; n1 = pb[base + 64]; n2 = pb[base + 128]; n3 = pb[base + 192];
    }
    KPROC(a0, g*4+0) KPROC(a1, g*4+1) KPROC(a2, g*4+2) KPROC(a3, g*4+3)
    a0 = n0; a1 = n1; a2 = n2; a3 = n3;
  }
#undef KPROC

  if (lane < KNN) knn_idx[(size_t)q * KNN + lane] = (int)kidx;
}

// ---------------- main kernel v5: scalar-pipe weights, fold-tree K-reduce ----------
// gamma = uA_i - uB_j + Wg@delta ; alpha = uC_j + delta ; delta recomputed on the fly.
// comb[c*68] = [weff_c (4) | Wg[o][c] for o=0..63] -> all wave-uniform -> s_load.
__global__ void __launch_bounds__(256, 4)
k_main5(const float* __restrict__ xyz,
        const float* __restrict__ feat,
        const int* __restrict__ knn_idx,
        const float* __restrict__ uA, const float* __restrict__ uB, const float* __restrict__ uC,
        const float* __restrict__ comb,
        const float* __restrict__ W2g, const float* __restrict__ b2g,
        float* __restrict__ out)
{
  __shared__ float sW2[64 * 68];      // W2 rows, +68 pad
  __shared__ float sB2[64];
  __shared__ float sY[16 * 68];       // per-point reduced acc, pad 68 floats/point

  const int tid = threadIdx.x;
  {
    #pragma unroll
    for (int it = 0; it < 16; ++it) {
      const int e = it*256 + tid;     // e = o*64 + c
      sW2[(e >> 6)*68 + (e & 63)] = W2g[e];
    }
    if (tid < 64) sB2[tid] = b2g[tid];
  }
  __syncthreads();

  const int lane  = tid & 63;
  const int kslot = lane & 15;
  const int plocal = (tid >> 6) * 4 + (lane >> 4);         // 0..15 in block
  const int point = blockIdx.x * 16 + plocal;
  const int b     = point >> 13;
  const int i     = point & (NP - 1);
  const size_t irow = (size_t)point * D;

  const int j = knn_idx[(size_t)blockIdx.x * 256 + tid];
  const size_t jrow = ((size_t)(b * NP + j)) * D;

  const float* xb = xyz + (size_t)b * NP * 3;
  const float dx = xb[i*3+0] - xb[j*3+0];
  const float dy = xb[i*3+1] - xb[j*3+1];
  const float dz = xb[i*3+2] - xb[j*3+2];

  // ---- gamma init: uA_i - uB_j ----
  float gamma[64];
  {
    const float4* ua = (const float4*)(uA + irow);
    const float4* ub = (const float4*)(uB + jrow);
    #pragma unroll
    for (int cc = 0; cc < 16; ++cc) {
      float4 a = ua[cc];
      float4 v = ub[cc];
      gamma[cc*4+0] = a.x - v.x; gamma[cc*4+1] = a.y - v.y;
      gamma[cc*4+2] = a.z - v.z; gamma[cc*4+3] = a.w - v.w;
    }
  }

  // ---- gamma += Wg @ delta; weights via uniform scalar loads ----
  #pragma unroll 4
  for (int c = 0; c < 64; ++c) {
    const float4* rec = (const float4*)(comb + c*68);      // uniform -> s_load
    float4 wf = rec[0];
    float t = fmaf(wf.z, dz, fmaf(wf.y, dy, fmaf(wf.x, dx, wf.w)));
    float d = fmaxf(t, 0.f);
    #pragma unroll
    for (int o4 = 0; o4 < 16; ++o4) {
      float4 w = rec[1 + o4];
      gamma[o4*4+0] = fmaf(w.x, d, gamma[o4*4+0]);
      gamma[o4*4+1] = fmaf(w.y, d, gamma[o4*4+1]);
      gamma[o4*4+2] = fmaf(w.z, d, gamma[o4*4+2]);
      gamma[o4*4+3] = fmaf(w.w, d, gamma[o4*4+3]);
    }
  }

  // ---- lane-local softmax over 64 channels ----
  float m0 = gamma[0], m1 = gamma[1], m2 = gamma[2], m3 = gamma[3];
  #pragma unroll
  for (int c = 4; c < 64; c += 4) {
    m0 = fmaxf(m0, gamma[c+0]); m1 = fmaxf(m1, gamma[c+1]);
    m2 = fmaxf(m2, gamma[c+2]); m3 = fmaxf(m3, gamma[c+3]);
  }
  const float m = fmaxf(fmaxf(m0, m1), fmaxf(m2, m3));
  float s0 = 0.f, s1 = 0.f, s2 = 0.f, s3 = 0.f;
  #pragma unroll
  for (int c = 0; c < 64; c += 4) {
    gamma[c+0] = __expf(gamma[c+0] - m); s0 += gamma[c+0];
    gamma[c+1] = __expf(gamma[c+1] - m); s1 += gamma[c+1];
    gamma[c+2] = __expf(gamma[c+2] - m); s2 += gamma[c+2];
    gamma[c+3] = __expf(gamma[c+3] - m); s3 += gamma[c+3];
  }
  const float inv = 1.0f / ((s0 + s1) + (s2 + s3));

  // ---- v[c] = rho * (uC_j + delta); delta recomputed from scalar recs ----
  {
    const float4* uc = (const float4*)(uC + jrow);
    #pragma unroll
    for (int cc = 0; cc < 16; ++cc) {
      float4 av = uc[cc];
      float avv[4] = {av.x, av.y, av.z, av.w};
      #pragma unroll
      for (int r = 0; r < 4; ++r) {
        const int c = cc*4 + r;
        const float4* rec = (const float4*)(comb + c*68);
        float4 wf = rec[0];
        float t = fmaf(wf.z, dz, fmaf(wf.y, dy, fmaf(wf.x, dx, wf.w)));
        float d = fmaxf(t, 0.f);
        gamma[c] = gamma[c] * inv * (avv[r] + d);
      }
    }
  }

  // ---- fold-tree reduce over the 16 kslot lanes ----
  // stage m: keep (kslot&m ? upper : lower) half, send the other; channel of final
  // y[i] = 4*kslot + i.
  float t8[32];
  {
    const bool hi = (kslot & 8) != 0;
    #pragma unroll
    for (int i2 = 0; i2 < 32; ++i2) {
      float sendv = hi ? gamma[i2] : gamma[i2+32];
      float keepv = hi ? gamma[i2+32] : gamma[i2];
      t8[i2] = keepv + __shfl_xor(sendv, 8, 64);
    }
  }
  float t4[16];
  {
    const bool hi = (kslot & 4) != 0;
    #pragma unroll
    for (int i2 = 0; i2 < 16; ++i2) {
      float sendv = hi ? t8[i2] : t8[i2+16];
      float keepv = hi ? t8[i2+16] : t8[i2];
      t4[i2] = keepv + __shfl_xor(sendv, 4, 64);
    }
  }
  float t2[8];
  {
    const bool hi = (kslot & 2) != 0;
    #pragma unroll
    for (int i2 = 0; i2 < 8; ++i2) {
      float sendv = hi ? t4[i2] : t4[i2+8];
      float keepv = hi ? t4[i2+8] : t4[i2];
      t2[i2] = keepv + __shfl_xor(sendv, 2, 64);
    }
  }
  float y0, y1, y2, y3;
  {
    const bool hi = (kslot & 1) != 0;
    float s0v = hi ? t2[0] : t2[4];
    float s1v = hi ? t2[1] : t2[5];
    float s2v = hi ? t2[2] : t2[6];
    float s3v = hi ? t2[3] : t2[7];
    float k0 = hi ? t2[4] : t2[0];
    float k1 = hi ? t2[5] : t2[1];
    float k2 = hi ? t2[6] : t2[2];
    float k3 = hi ? t2[7] : t2[3];
    y0 = k0 + __shfl_xor(s0v, 1, 64);
    y1 = k1 + __shfl_xor(s1v, 1, 64);
    y2 = k2 + __shfl_xor(s2v, 1, 64);
    y3 = k3 + __shfl_xor(s3v, 1, 64);
  }

  // ---- redistribute y across the 16 lanes via padded LDS ----
  ((float4*)sY)[plocal * 17 + kslot] = make_float4(y0, y1, y2, y3);
  __syncthreads();
  float y[64];
  {
    const float4* yp = (const float4*)sY + plocal * 17;
    #pragma unroll
    for (int o4 = 0; o4 < 16; ++o4) {
      float4 v = yp[o4];
      y[o4*4+0] = v.x; y[o4*4+1] = v.y; y[o4*4+2] = v.z; y[o4*4+3] = v.w;
    }
  }

  // ---- epilogue: out = y @ W2^T + b2 + feat; lane kslot does 4 channels ----
  const int oc = kslot * 4;
  float o0 = sB2[oc+0], o1 = sB2[oc+1], o2 = sB2[oc+2], o3 = sB2[oc+3];
  {
    const float4* r0 = (const float4*)(sW2 + (oc+0)*68);
    const float4* r1 = (const float4*)(sW2 + (oc+1)*68);
    const float4* r2 = (const float4*)(sW2 + (oc+2)*68);
    const float4* r3 = (const float4*)(sW2 + (oc+3)*68);
    #pragma unroll
    for (int c4 = 0; c4 < 16; ++c4) {
      float4 w0 = r0[c4], w1 = r1[c4], w2 = r2[c4], w3 = r3[c4];
      o0 = fmaf(w0.x, y[c4*4+0], o0); o0 = fmaf(w0.y, y[c4*4+1], o0);
      o0 = fmaf(w0.z, y[c4*4+2], o0); o0 = fmaf(w0.w, y[c4*4+3], o0);
      o1 = fmaf(w1.x, y[c4*4+0], o1); o1 = fmaf(w1.y, y[c4*4+1], o1);
      o1 = fmaf(w1.z, y[c4*4+2], o1); o1 = fmaf(w1.w, y[c4*4+3], o1);
      o2 = fmaf(w2.x, y[c4*4+0], o2); o2 = fmaf(w2.y, y[c4*4+1], o2);
      o2 = fmaf(w2.z, y[c4*4+2], o2); o2 = fmaf(w2.w, y[c4*4+3], o2);
      o3 = fmaf(w3.x, y[c4*4+0], o3); o3 = fmaf(w3.y, y[c4*4+1], o3);
      o3 = fmaf(w3.z, y[c4*4+2], o3); o3 = fmaf(w3.w, y[c4*4+3], o3);
    }
  }
  float4 fv = ((const float4*)(feat + irow))[kslot];
  ((float4*)(out + irow))[kslot] = make_float4(o0 + fv.x, o1 + fv.y, o2 + fv.z, o3 + fv.w);
}

extern "C" void kernel_launch(void* const* d_in, const int* in_sizes, int n_in,
                              void* d_out, int out_size, void* d_ws, size_t ws_size,
                              hipStream_t stream) {
  const float* xyz  = (const float*)d_in[0];
  const float* feat = (const float*)d_in[1];
  // d_in[2] = k (int32) == 16, compile-time constant here
  const float* W1   = (const float*)d_in[3];
  const float* b1   = (const float*)d_in[4];
  const float* Wphi = (const float*)d_in[5];
  const float* bphi = (const float*)d_in[6];
  const float* Wpsi = (const float*)d_in[7];
  const float* bpsi = (const float*)d_in[8];
  const float* Wal  = (const float*)d_in[9];
  const float* bal  = (const float*)d_in[10];
  const float* Wg   = (const float*)d_in[11];
  const float* bg   = (const float*)d_in[12];
  const float* Wd1  = (const float*)d_in[13];
  const float* bd1  = (const float*)d_in[14];
  const float* Wd2  = (const float*)d_in[15];
  const float* bd2  = (const float*)d_in[16];
  const float* W2   = (const float*)d_in[17];
  const float* b2   = (const float*)d_in[18];

  float* out = (float*)d_out;

  // workspace (f32 words): uA | uB | uC | knn_idx | pts4 | weff | folds | comb
  const size_t NPT = (size_t)NB * NP;     // 16384
  float* uA = (float*)d_ws;
  float* uB = uA + NPT * D;
  float* uC = uB + NPT * D;
  int* knn_idx = (int*)(uC + NPT * D);
  float4* pts4 = (float4*)(knn_idx + NPT * KNN);
  float4* weff = pts4 + NPT;
  float* Af  = (float*)(weff + 64);
  float* dAv = Af + 4096;
  float* Bf  = dAv + 64;
  float* dBv = Bf + 4096;
  float* Cf  = dBv + 64;
  float* dCv = Cf + 4096;
  float* comb = dCv + 64;                 // 64*68 floats

  // output 0: points_xyz passthrough (f32)
  hipMemcpyAsync(d_out, d_in[0], NPT * 3 * sizeof(float),
                 hipMemcpyDeviceToDevice, stream);

  k_prep<<<NPT / 256, 256, 0, stream>>>(xyz, pts4);
  k_fold<<<1, 64, 0, stream>>>(Wd1, bd1, Wd2, bd2, weff);
  k_fold3<<<1, 256, 0, stream>>>(weff, Wg, comb);
  k_fold2<<<3, 256, 0, stream>>>(Wg, bg, Wphi, bphi, Wpsi, bpsi, Wal, bal, W1, b1,
                                 Af, dAv, Bf, dBv, Cf, dCv);
  k_transform3<<<dim3(64, 12), 256, 0, stream>>>(feat, Af, dAv, Bf, dBv, Cf, dCv,
                                                 uA, uB, uC);
  k_knn5<<<NPT / 4, 256, 0, stream>>>(pts4, knn_idx);
  k_main5<<<NPT / 16, 256, 0, stream>>>(xyz, feat, knn_idx, uA, uB, uC, comb,
                                        W2, b2, out + NPT * 3);
}